// Round 1
// baseline (205.083 us; speedup 1.0000x reference)
//
#include <hip/hip_runtime.h>

// CalWeight: out[b,j] = phi[b,j] - phi[b,(j+1)%N]
//   phi[b,j] = atan2(verts_y[b,j] - row[b], verts_x[b,j] - col[b])
// x layout per row: [col, row, v0x, v0y, ... v1023x, v1023y], stride 2050 floats.
//
// R1: replace libm atan2f (__ocml_atan2_f32: IEEE-correct divide via
// div_scale/div_fmas/div_fixup + inf/nan handling, ~50+ VALU instrs, long
// serial chain) with a branchless fast atan2: v_rcp_f32 hardware reciprocal
// + SLEEF degree-8 minimax poly on [0,1] + 3 selects. ~22 VALU + 1 trans.
// Max added error ~1e-6 rad, far under the passing absmax (0.03125, which is
// conditioning-dominated near-center vertices, identical in both versions).

#define NVERT 1024
#define ROWSTRIDE (2 + 2 * NVERT)
#define BLK 256

__device__ __forceinline__ float fast_atan2f(float dy, float dx) {
    const float ax = __builtin_fabsf(dx);
    const float ay = __builtin_fabsf(dy);
    const float mx = fmaxf(ax, ay);
    const float mn = fminf(ax, ay);
    // t in [0,1]; v_rcp_f32 (~1 ulp) instead of IEEE divide chain.
    float t = mn * __builtin_amdgcn_rcpf(mx);
    t = (mx == 0.0f) ? 0.0f : t;  // atan2(0,0) -> 0, keep NaN out
    const float s = t * t;
    // SLEEF atanf minimax polynomial (valid on t in [-1,1]).
    float u =                  0.00282363896258175373077393f;
    u = __builtin_fmaf(u, s, -0.0159569028764963150024414f);
    u = __builtin_fmaf(u, s,  0.0425049886107444763183594f);
    u = __builtin_fmaf(u, s, -0.0748900920152664184570312f);
    u = __builtin_fmaf(u, s,  0.106347933411598205566406f);
    u = __builtin_fmaf(u, s, -0.142027363181114196777344f);
    u = __builtin_fmaf(u, s,  0.199926957488059997558594f);
    u = __builtin_fmaf(u, s, -0.333331018686294555664062f);
    float r = __builtin_fmaf(s * u, t, t);            // atan(t), r in [0, pi/4]
    r = (ay > ax) ? (1.5707963267948966f - r) : r;    // reflect: angle vs x-axis
    r = (dx < 0.0f) ? (3.1415926535897931f - r) : r;  // left half-plane
    return __builtin_copysignf(r, dy);                // lower half-plane
}

__global__ __launch_bounds__(BLK) void calweight_kernel(const float* __restrict__ x,
                                                        float* __restrict__ out) {
    const int b = blockIdx.x;
    const int t = threadIdx.x;

    const float* __restrict__ xr = x + (size_t)b * ROWSTRIDE;
    const float colv = xr[0];
    const float rowv = xr[1];

    __shared__ float phi[NVERT];

    // Phase 1: coalesced float2 loads (one vertex per load), compute phi.
    // (b*2050 + 2)*4 bytes is always 8B-aligned, so float2* cast is safe.
    const float2* __restrict__ verts = (const float2*)(xr + 2);
#pragma unroll
    for (int k = 0; k < NVERT / BLK; ++k) {
        const int j = t + k * BLK;
        const float2 v = verts[j];
        phi[j] = fast_atan2f(v.y - rowv, v.x - colv);
    }
    __syncthreads();

    // Phase 2: each thread produces 4 consecutive outputs as one float4 store.
    float* __restrict__ orow = out + (size_t)b * NVERT;
    const int j0 = 4 * t;
    const float4 p = ((const float4*)phi)[t];
    const float pn = phi[(j0 + 4) & (NVERT - 1)];  // wrap: j=1023 -> phi[0]
    float4 r;
    r.x = p.x - p.y;
    r.y = p.y - p.z;
    r.z = p.z - p.w;
    r.w = p.w - pn;
    ((float4*)orow)[t] = r;
}

extern "C" void kernel_launch(void* const* d_in, const int* in_sizes, int n_in,
                              void* d_out, int out_size, void* d_ws, size_t ws_size,
                              hipStream_t stream) {
    const float* x = (const float*)d_in[0];
    float* out = (float*)d_out;
    const int B = in_sizes[0] / ROWSTRIDE;  // 16384
    calweight_kernel<<<B, BLK, 0, stream>>>(x, out);
}